// Round 3
// baseline (536.313 us; speedup 1.0000x reference)
//
#include <hip/hip_runtime.h>

// Problem constants (B=4, N=512, M=32768, D=1024, H=16, hd=64, K=32)
#define BTOK   2048
#define DDIM   1024
#define MKEYS  32768
#define NHEAD  16
#define HDIM   64
#define KSEL   32

typedef __attribute__((ext_vector_type(4))) float f32x4;
typedef __attribute__((ext_vector_type(8))) short bf16x8;   // 8 bf16 in 4 VGPRs

// workspace layout (float offsets)
#define WS_QFULL 0                               // 2M floats; later aliased by raw
#define WS_CTXB  (2*1024*1024)                   // ctx in bf16: 2M ushorts = 1M floats
#define WS_S     (WS_CTXB + 1024*1024)
#define WS_S2    (WS_S + MKEYS)
#define WS_QM    (WS_S2 + MKEYS)
#define WS_KP    (WS_QM + BTOK)
#define WS_VP    (WS_KP + 64*1024)
#define WS_IDX   (WS_VP + 64*1024)               // 64 ints
#define WS_XB    (WS_IDX + 64)                   // x bf16: 2M ushorts = 1M floats
#define WS_WQB   (WS_XB + 1024*1024)             // each W bf16: 1M ushorts = 512K floats
#define WS_WKB   (WS_WQB + 512*1024)
#define WS_WVB   (WS_WKB + 512*1024)
#define WS_WOB   (WS_WVB + 512*1024)
#define WS_CVEC  (WS_WOB + 512*1024)             // colmean(Wq): 1024 floats
#define WS_RAW   WS_QFULL

// d_out layout (float offsets)
#define OUT_AVG  (BTOK * DDIM)
#define OUT_IDX  (OUT_AVG + BTOK * KSEL)

__device__ __forceinline__ unsigned short f2bf(float f) {   // RNE float->bf16
    unsigned u = __float_as_uint(f);
    u += 0x7fffu + ((u >> 16) & 1u);
    return (unsigned short)(u >> 16);
}

// ---------------------------------------------------------------------------
// 0) fused prep: [0,8192) reduce_keys (4 rows/block) | [8192,14336) fp32->bf16
//    casts of x,Wq,Wk,Wv,Wo | [14336,14340) colmean(Wq) -> cvec
__global__ __launch_bounds__(256) void prep_kernel(
        const float* __restrict__ mk, const float* __restrict__ x,
        const float* __restrict__ Wq, const float* __restrict__ Wk,
        const float* __restrict__ Wv, const float* __restrict__ Wo,
        float* __restrict__ s, float* __restrict__ s2,
        unsigned short* __restrict__ xb, unsigned short* __restrict__ wqb,
        unsigned short* __restrict__ wkb, unsigned short* __restrict__ wvb,
        unsigned short* __restrict__ wob, float* __restrict__ cvec) {
    const int b = blockIdx.x, t = threadIdx.x;
    if (b < 8192) {
        const int w = t >> 6, l = t & 63;
        const int row = b * 4 + w;
        const float* r = mk + (size_t)row * DDIM;
        float sum = 0.f, sq = 0.f;
#pragma unroll
        for (int i = 0; i < 4; ++i) {
            float4 v = *(const float4*)(r + i * 256 + l * 4);
            sum += v.x + v.y + v.z + v.w;
            sq  += v.x * v.x + v.y * v.y + v.z * v.z + v.w * v.w;
        }
#pragma unroll
        for (int off = 32; off; off >>= 1) {
            sum += __shfl_down(sum, off);
            sq  += __shfl_down(sq, off);
        }
        if (l == 0) {
            float val = sum / sqrtf(sq);
            s[row] = val; s2[row] = -val;
        }
    } else if (b < 14336) {
        const float* src; unsigned short* dst; int blk;
        if (b < 10240)      { src = x;  dst = xb;  blk = b - 8192; }
        else if (b < 11264) { src = Wq; dst = wqb; blk = b - 10240; }
        else if (b < 12288) { src = Wk; dst = wkb; blk = b - 11264; }
        else if (b < 13312) { src = Wv; dst = wvb; blk = b - 12288; }
        else                { src = Wo; dst = wob; blk = b - 13312; }
        const size_t base = (size_t)blk * 1024 + t * 4;
        float4 v = *(const float4*)(src + base);
        ushort4 o;
        o.x = f2bf(v.x); o.y = f2bf(v.y); o.z = f2bf(v.z); o.w = f2bf(v.w);
        *(ushort4*)(dst + base) = o;
    } else {
        const int d = (b - 14336) * 256 + t;
        float acc = 0.f;
#pragma unroll 8
        for (int o = 0; o < 1024; ++o) acc += Wq[(size_t)o * 1024 + d];
        cvec[d] = acc * (1.f / 1024.f);
    }
}

// ---------------------------------------------------------------------------
// 1) qm[row] = x[row] . cvec  (fp32 — protects the selection sign exactly;
//    == mean_o(q_full[row,o]) up to summation order)
__global__ __launch_bounds__(256) void qm_dot(const float* __restrict__ x,
                                              const float* __restrict__ cvec,
                                              float* __restrict__ qm) {
    const int w = threadIdx.x >> 6, l = threadIdx.x & 63;
    const int row = blockIdx.x * 4 + w;
    const float* r = x + (size_t)row * DDIM;
    float s = 0.f;
#pragma unroll
    for (int i = 0; i < 4; ++i) {
        float4 v = *(const float4*)(r + i * 256 + l * 4);
        float4 c = *(const float4*)(cvec + i * 256 + l * 4);
        s += v.x * c.x + v.y * c.y + v.z * c.z + v.w * c.w;
    }
#pragma unroll
    for (int off = 32; off; off >>= 1) s += __shfl_down(s, off);
    if (l == 0) qm[row] = s;
}

// ---------------------------------------------------------------------------
// 2) radix-select top-32 (value desc, tie -> lower index) of 32768 floats.
__global__ __launch_bounds__(1024) void topk_radix(const float* __restrict__ sarr,
                                                   int* __restrict__ idx_out) {
    const float* s = sarr + blockIdx.x * MKEYS;
    int* out = idx_out + blockIdx.x * KSEL;
    const int t = threadIdx.x;

    __shared__ int   hist[4096];
    __shared__ int   csum[64];
    __shared__ int   binB_s;
    __shared__ int   ccnt;
    __shared__ float cval[1024];
    __shared__ int   cidx[1024];

    for (int i = t; i < 4096; i += 1024) hist[i] = 0;
    if (t == 0) ccnt = 0;
    __syncthreads();

    for (int j = 0; j < 32; ++j) {
        unsigned u = __float_as_uint(s[t + j * 1024]);
        unsigned k = u ^ (unsigned)(((int)u >> 31) | (int)0x80000000);
        atomicAdd(&hist[k >> 20], 1);
    }
    __syncthreads();

    if (t < 64) {
        int acc = 0;
        for (int j = 0; j < 64; ++j) acc += hist[t * 64 + j];
        csum[t] = acc;
    }
    __syncthreads();
    if (t == 0) {
        int acc = 0, cb = 63;
        for (; cb > 0; --cb) {
            if (acc + csum[cb] >= KSEL) break;
            acc += csum[cb];
        }
        int b = cb * 64 + 63;
        for (; b > cb * 64; --b) {
            if (acc + hist[b] >= KSEL) break;
            acc += hist[b];
        }
        binB_s = b;
    }
    __syncthreads();
    const unsigned binB = (unsigned)binB_s;

    for (int j = 0; j < 32; ++j) {
        const int ii = t + j * 1024;
        float v = s[ii];
        unsigned u = __float_as_uint(v);
        unsigned k = u ^ (unsigned)(((int)u >> 31) | (int)0x80000000);
        if ((k >> 20) >= binB) {
            int p = atomicAdd(&ccnt, 1);
            if (p < 1024) { cval[p] = v; cidx[p] = ii; }
        }
    }
    __syncthreads();

    const int n = min(ccnt, 1024);
    if (t < 64) {
        for (int iter = 0; iter < KSEL; ++iter) {
            float bv = -INFINITY; int bi = 0x7fffffff; int bs = -1;
            for (int j = t; j < n; j += 64) {
                float v = cval[j]; int ii = cidx[j];
                if (v > bv || (v == bv && ii < bi)) { bv = v; bi = ii; bs = j; }
            }
#pragma unroll
            for (int off = 32; off; off >>= 1) {
                float ov = __shfl_down(bv, off);
                int   oi = __shfl_down(bi, off);
                int   os = __shfl_down(bs, off);
                if (ov > bv || (ov == bv && oi < bi)) { bv = ov; bi = oi; bs = os; }
            }
            bs = __shfl(bs, 0);
            if (t == 0) {
                out[iter] = bi;
                cval[bs] = -INFINITY;
            }
        }
    }
}

// ---------------------------------------------------------------------------
// 3) bf16 MFMA GEMM, no LDS: C[M,1024] = A[M,1024] x B[1024,1024]^T.
//    grid (N/128, M/128), 256 thr = 4 waves in 2x2, each wave 64x64 via
//    4x4 grid of 16x16x32 MFMAs; fragments read straight from L2.
__global__ __launch_bounds__(256) void gemm_mfma(const unsigned short* __restrict__ A,
                                                 const unsigned short* __restrict__ Bm,
                                                 float* __restrict__ C) {
    const int lane = threadIdx.x & 63, wave = threadIdx.x >> 6;
    const int quad = lane >> 4, l16 = lane & 15;
    const int m0 = blockIdx.y * 128 + (wave >> 1) * 64;
    const int n0 = blockIdx.x * 128 + (wave & 1) * 64;
    const unsigned short* ap = A + (size_t)(m0 + l16) * DDIM + quad * 8;
    const unsigned short* bp = Bm + (size_t)(n0 + l16) * DDIM + quad * 8;

    const f32x4 fzero = {0.f, 0.f, 0.f, 0.f};
    f32x4 acc[4][4];
#pragma unroll
    for (int i = 0; i < 4; ++i)
#pragma unroll
        for (int j = 0; j < 4; ++j) acc[i][j] = fzero;

    for (int k0 = 0; k0 < DDIM; k0 += 32) {
        bf16x8 af[4], bfr[4];
#pragma unroll
        for (int i = 0; i < 4; ++i)
            af[i] = *(const bf16x8*)(ap + (size_t)i * 16 * DDIM + k0);
#pragma unroll
        for (int j = 0; j < 4; ++j)
            bfr[j] = *(const bf16x8*)(bp + (size_t)j * 16 * DDIM + k0);
#pragma unroll
        for (int i = 0; i < 4; ++i)
#pragma unroll
            for (int j = 0; j < 4; ++j)
                acc[i][j] = __builtin_amdgcn_mfma_f32_16x16x32_bf16(af[i], bfr[j], acc[i][j], 0, 0, 0);
    }
    // C/D layout: col = lane&15, row = quad*4 + reg
#pragma unroll
    for (int i = 0; i < 4; ++i) {
        const int row0 = m0 + i * 16 + quad * 4;
#pragma unroll
        for (int j = 0; j < 4; ++j) {
            const int col = n0 + j * 16 + l16;
#pragma unroll
            for (int r = 0; r < 4; ++r)
                C[(size_t)(row0 + r) * DDIM + col] = acc[i][j][r];
        }
    }
}

// ---------------------------------------------------------------------------
// 4) K/V projection of the 64 selected rows (gather fp32 -> bf16 in-register).
//    grid (4, 2): x = n-tile of 256, y = which (K vs V). Wave does 64x64.
__global__ __launch_bounds__(256) void gemm_kv_mfma(
        const float* __restrict__ mk, const float* __restrict__ mv,
        const unsigned short* __restrict__ wkb, const unsigned short* __restrict__ wvb,
        float* __restrict__ kp, float* __restrict__ vp,
        const int* __restrict__ gidx) {
    const float* A = blockIdx.y ? mv : mk;
    const unsigned short* Bm = blockIdx.y ? wvb : wkb;
    float* C = blockIdx.y ? vp : kp;
    const int lane = threadIdx.x & 63, wave = threadIdx.x >> 6;
    const int quad = lane >> 4, l16 = lane & 15;
    const int n0 = blockIdx.x * 256 + wave * 64;

    size_t arow[4];
#pragma unroll
    for (int i = 0; i < 4; ++i) arow[i] = (size_t)gidx[i * 16 + l16] * DDIM;

    const f32x4 fzero = {0.f, 0.f, 0.f, 0.f};
    f32x4 acc[4][4];
#pragma unroll
    for (int i = 0; i < 4; ++i)
#pragma unroll
        for (int j = 0; j < 4; ++j) acc[i][j] = fzero;

    for (int k0 = 0; k0 < DDIM; k0 += 32) {
        bf16x8 af[4], bfr[4];
#pragma unroll
        for (int i = 0; i < 4; ++i) {
            const float* p = A + arow[i] + k0 + quad * 8;
            float4 v0 = *(const float4*)(p);
            float4 v1 = *(const float4*)(p + 4);
            af[i][0] = (short)f2bf(v0.x); af[i][1] = (short)f2bf(v0.y);
            af[i][2] = (short)f2bf(v0.z); af[i][3] = (short)f2bf(v0.w);
            af[i][4] = (short)f2bf(v1.x); af[i][5] = (short)f2bf(v1.y);
            af[i][6] = (short)f2bf(v1.z); af[i][7] = (short)f2bf(v1.w);
        }
#pragma unroll
        for (int j = 0; j < 4; ++j)
            bfr[j] = *(const bf16x8*)(Bm + (size_t)(n0 + j * 16 + l16) * DDIM + k0 + quad * 8);
#pragma unroll
        for (int i = 0; i < 4; ++i)
#pragma unroll
            for (int j = 0; j < 4; ++j)
                acc[i][j] = __builtin_amdgcn_mfma_f32_16x16x32_bf16(af[i], bfr[j], acc[i][j], 0, 0, 0);
    }
#pragma unroll
    for (int i = 0; i < 4; ++i) {
        const int row0 = i * 16 + quad * 4;
#pragma unroll
        for (int j = 0; j < 4; ++j) {
            const int col = n0 + j * 16 + l16;
#pragma unroll
            for (int r = 0; r < 4; ++r)
                C[(size_t)(row0 + r) * DDIM + col] = acc[i][j][r];
        }
    }
}

// ---------------------------------------------------------------------------
// 5) attention: one block per token; writes ctx as bf16 (feeds the o-GEMM),
//    plus avg_attn and sel_idx (as float) straight into d_out.
__global__ __launch_bounds__(256) void attention_kernel(const float* __restrict__ q_full,
                                                        const float* __restrict__ qm,
                                                        const float* __restrict__ kp,
                                                        const float* __restrict__ vp,
                                                        const int* __restrict__ idx_list,
                                                        unsigned short* __restrict__ ctxb,
                                                        float* __restrict__ out) {
    const int bn = blockIdx.x;
    const int t = threadIdx.x;
    __shared__ float qs[DDIM];
    __shared__ float sc[NHEAD][KSEL + 1];
    __shared__ int selbase_s;

    *(float4*)(qs + t * 4) = *(const float4*)(q_full + (size_t)bn * DDIM + t * 4);
    if (t == 0) selbase_s = (qm[bn] > 0.0f) ? 0 : KSEL;
    __syncthreads();
    const int selbase = selbase_s;

#pragma unroll
    for (int p = 0; p < 2; ++p) {
        const int pair = t + p * 256;
        const int h = pair >> 5, k = pair & 31;
        const float* kr = kp + (size_t)(selbase + k) * DDIM + h * HDIM;
        const float* qr = qs + h * HDIM;
        float acc = 0.f;
#pragma unroll
        for (int i = 0; i < 16; ++i) {
            float4 kv = *(const float4*)(kr + i * 4);
            acc += qr[i * 4 + 0] * kv.x + qr[i * 4 + 1] * kv.y +
                   qr[i * 4 + 2] * kv.z + qr[i * 4 + 3] * kv.w;
        }
        sc[h][k] = acc * 0.125f;
    }
    __syncthreads();

    if (t < NHEAD) {
        float m = -INFINITY;
        for (int k = 0; k < KSEL; ++k) m = fmaxf(m, sc[t][k]);
        float ssum = 0.f;
        for (int k = 0; k < KSEL; ++k) { float e = __expf(sc[t][k] - m); sc[t][k] = e; ssum += e; }
        float inv = 1.f / ssum;
        for (int k = 0; k < KSEL; ++k) sc[t][k] *= inv;
    }
    __syncthreads();

#pragma unroll
    for (int c = 0; c < 4; ++c) {
        const int o = c * 256 + t;
        const int h = o >> 6;
        float acc = 0.f;
        for (int k = 0; k < KSEL; ++k)
            acc += sc[h][k] * vp[(size_t)(selbase + k) * DDIM + o];
        ctxb[(size_t)bn * DDIM + o] = f2bf(acc);
    }

    if (t < KSEL) {
        float a = 0.f;
#pragma unroll
        for (int h = 0; h < NHEAD; ++h) a += sc[h][t];
        out[OUT_AVG + bn * KSEL + t] = a * (1.f / 16.f);
        out[OUT_IDX + bn * KSEL + t] = (float)idx_list[selbase + t];
    }
}

// ---------------------------------------------------------------------------
// 6) LayerNorm row kernel
__global__ __launch_bounds__(256) void ln_kernel(const float* __restrict__ raw,
                                                 const float* __restrict__ bo,
                                                 const float* __restrict__ gamma,
                                                 const float* __restrict__ beta,
                                                 float* __restrict__ out) {
    const int row = blockIdx.x;
    const int t = threadIdx.x;
    float4 v = *(const float4*)(raw + (size_t)row * DDIM + t * 4);
    float4 b = *(const float4*)(bo + t * 4);
    v.x += b.x; v.y += b.y; v.z += b.z; v.w += b.w;
    float s  = v.x + v.y + v.z + v.w;
    float ss = v.x * v.x + v.y * v.y + v.z * v.z + v.w * v.w;
#pragma unroll
    for (int off = 32; off; off >>= 1) {
        s  += __shfl_down(s, off);
        ss += __shfl_down(ss, off);
    }
    __shared__ float rs[4], rss[4];
    const int w = t >> 6, l = t & 63;
    if (l == 0) { rs[w] = s; rss[w] = ss; }
    __syncthreads();
    if (t == 0) {
        rs[0]  = rs[0] + rs[1] + rs[2] + rs[3];
        rss[0] = rss[0] + rss[1] + rss[2] + rss[3];
    }
    __syncthreads();
    const float mu  = rs[0] * (1.f / 1024.f);
    const float var = rss[0] * (1.f / 1024.f) - mu * mu;
    const float rstd = rsqrtf(var + 1e-5f);
    float4 g  = *(const float4*)(gamma + t * 4);
    float4 be = *(const float4*)(beta + t * 4);
    float4 o;
    o.x = (v.x - mu) * rstd * g.x + be.x;
    o.y = (v.y - mu) * rstd * g.y + be.y;
    o.z = (v.z - mu) * rstd * g.z + be.z;
    o.w = (v.w - mu) * rstd * g.w + be.w;
    *(float4*)(out + (size_t)row * DDIM + t * 4) = o;
}

// ---------------------------------------------------------------------------
extern "C" void kernel_launch(void* const* d_in, const int* in_sizes, int n_in,
                              void* d_out, int out_size, void* d_ws, size_t ws_size,
                              hipStream_t stream) {
    const float* x     = (const float*)d_in[0];
    const float* mk    = (const float*)d_in[1];
    const float* mv    = (const float*)d_in[2];
    const float* Wq    = (const float*)d_in[3];
    const float* Wk    = (const float*)d_in[4];
    const float* Wv    = (const float*)d_in[5];
    const float* Wo    = (const float*)d_in[6];
    const float* bo    = (const float*)d_in[7];
    const float* gamma = (const float*)d_in[8];
    const float* beta  = (const float*)d_in[9];

    float* ws  = (float*)d_ws;
    float* out = (float*)d_out;

    float* q_full          = ws + WS_QFULL;
    unsigned short* ctxb   = (unsigned short*)(ws + WS_CTXB);
    float* sarr            = ws + WS_S;
    float* qm              = ws + WS_QM;
    float* kp              = ws + WS_KP;
    float* vp              = ws + WS_VP;
    int*   idx             = (int*)(ws + WS_IDX);
    unsigned short* xb     = (unsigned short*)(ws + WS_XB);
    unsigned short* wqb    = (unsigned short*)(ws + WS_WQB);
    unsigned short* wkb    = (unsigned short*)(ws + WS_WKB);
    unsigned short* wvb    = (unsigned short*)(ws + WS_WVB);
    unsigned short* wob    = (unsigned short*)(ws + WS_WOB);
    float* cvec            = ws + WS_CVEC;
    float* raw             = ws + WS_RAW;   // aliases q_full (dead after attention)

    hipLaunchKernelGGL(prep_kernel, dim3(14340), dim3(256), 0, stream,
                       mk, x, Wq, Wk, Wv, Wo, sarr, sarr + MKEYS,
                       xb, wqb, wkb, wvb, wob, cvec);
    hipLaunchKernelGGL(qm_dot, dim3(BTOK / 4), dim3(256), 0, stream, x, cvec, qm);
    hipLaunchKernelGGL(topk_radix, dim3(2), dim3(1024), 0, stream, sarr, idx);
    hipLaunchKernelGGL(gemm_mfma, dim3(8, 16), dim3(256), 0, stream, xb, wqb, q_full);
    hipLaunchKernelGGL(gemm_kv_mfma, dim3(4, 2), dim3(256), 0, stream, mk, mv, wkb, wvb, kp, vp, idx);
    hipLaunchKernelGGL(attention_kernel, dim3(BTOK), dim3(256), 0, stream, q_full, qm, kp, vp, idx, ctxb, out);
    hipLaunchKernelGGL(gemm_mfma, dim3(8, 16), dim3(256), 0, stream, ctxb, wob, raw);
    hipLaunchKernelGGL(ln_kernel, dim3(BTOK), dim3(256), 0, stream, raw, bo, gamma, beta, out);
}

// Round 4
// 493.387 us; speedup vs baseline: 1.0870x; 1.0870x over previous
//
#include <hip/hip_runtime.h>

// Problem constants (B=4, N=512, M=32768, D=1024, H=16, hd=64, K=32)
#define BTOK   2048
#define DDIM   1024
#define MKEYS  32768
#define NHEAD  16
#define HDIM   64
#define KSEL   32

typedef __attribute__((ext_vector_type(4))) float f32x4;
typedef __attribute__((ext_vector_type(8))) short bf16x8;   // 8 bf16 in 4 VGPRs

// workspace layout (float offsets)
#define WS_QFULL 0                               // 2M floats; later aliased by raw
#define WS_CTXB  (2*1024*1024)                   // ctx in bf16: 2M ushorts = 1M floats
#define WS_S     (WS_CTXB + 1024*1024)
#define WS_S2    (WS_S + MKEYS)
#define WS_QM    (WS_S2 + MKEYS)
#define WS_KP    (WS_QM + BTOK)
#define WS_VP    (WS_KP + 64*1024)
#define WS_IDX   (WS_VP + 64*1024)               // 64 ints
#define WS_XB    (WS_IDX + 64)                   // x bf16: 2M ushorts = 1M floats
#define WS_WQB   (WS_XB + 1024*1024)             // each W bf16: 1M ushorts = 512K floats
#define WS_WKB   (WS_WQB + 512*1024)
#define WS_WVB   (WS_WKB + 512*1024)
#define WS_WOB   (WS_WVB + 512*1024)
#define WS_CVEC  (WS_WOB + 512*1024)             // colsum(Wq): 1024 floats
#define WS_RAW   WS_QFULL

// d_out layout (float offsets)
#define OUT_AVG  (BTOK * DDIM)
#define OUT_IDX  (OUT_AVG + BTOK * KSEL)

__device__ __forceinline__ unsigned short f2bf(float f) {   // RNE float->bf16
    unsigned u = __float_as_uint(f);
    u += 0x7fffu + ((u >> 16) & 1u);
    return (unsigned short)(u >> 16);
}

// ---------------------------------------------------------------------------
// 0) fused prep: [0,8192) reduce_keys (4 rows/block) | [8192,14336) fp32->bf16
//    casts of x,Wq,Wk,Wv,Wo | [14336,14400) colsum(Wq) -> cvec via atomics
//    (cvec must be zeroed before launch; done with hipMemsetAsync).
__global__ __launch_bounds__(256) void prep_kernel(
        const float* __restrict__ mk, const float* __restrict__ x,
        const float* __restrict__ Wq, const float* __restrict__ Wk,
        const float* __restrict__ Wv, const float* __restrict__ Wo,
        float* __restrict__ s, float* __restrict__ s2,
        unsigned short* __restrict__ xb, unsigned short* __restrict__ wqb,
        unsigned short* __restrict__ wkb, unsigned short* __restrict__ wvb,
        unsigned short* __restrict__ wob, float* __restrict__ cvec) {
    const int b = blockIdx.x, t = threadIdx.x;
    if (b < 8192) {
        const int w = t >> 6, l = t & 63;
        const int row = b * 4 + w;
        const float* r = mk + (size_t)row * DDIM;
        float sum = 0.f, sq = 0.f;
#pragma unroll
        for (int i = 0; i < 4; ++i) {
            float4 v = *(const float4*)(r + i * 256 + l * 4);
            sum += v.x + v.y + v.z + v.w;
            sq  += v.x * v.x + v.y * v.y + v.z * v.z + v.w * v.w;
        }
#pragma unroll
        for (int off = 32; off; off >>= 1) {
            sum += __shfl_down(sum, off);
            sq  += __shfl_down(sq, off);
        }
        if (l == 0) {
            float val = sum / sqrtf(sq);
            s[row] = val; s2[row] = -val;
        }
    } else if (b < 14336) {
        const float* src; unsigned short* dst; int blk;
        if (b < 10240)      { src = x;  dst = xb;  blk = b - 8192; }
        else if (b < 11264) { src = Wq; dst = wqb; blk = b - 10240; }
        else if (b < 12288) { src = Wk; dst = wkb; blk = b - 11264; }
        else if (b < 13312) { src = Wv; dst = wvb; blk = b - 12288; }
        else                { src = Wo; dst = wob; blk = b - 13312; }
        const size_t base = (size_t)blk * 1024 + t * 4;
        float4 v = *(const float4*)(src + base);
        ushort4 o;
        o.x = f2bf(v.x); o.y = f2bf(v.y); o.z = f2bf(v.z); o.w = f2bf(v.w);
        *(ushort4*)(dst + base) = o;
    } else {
        // colsum of Wq: 64 blocks x 16 rows, coalesced float4, atomic combine
        const int o0 = (b - 14336) * 16;
        float4 acc = make_float4(0.f, 0.f, 0.f, 0.f);
#pragma unroll
        for (int r = 0; r < 16; ++r) {
            float4 v = *(const float4*)(Wq + (size_t)(o0 + r) * 1024 + t * 4);
            acc.x += v.x; acc.y += v.y; acc.z += v.z; acc.w += v.w;
        }
        atomicAdd(&cvec[t * 4 + 0], acc.x);
        atomicAdd(&cvec[t * 4 + 1], acc.y);
        atomicAdd(&cvec[t * 4 + 2], acc.z);
        atomicAdd(&cvec[t * 4 + 3], acc.w);
    }
}

// ---------------------------------------------------------------------------
// 1) qm[row] = x[row] . cvec  (fp32 — only the SIGN is consumed downstream;
//    cvec holds colsum(Wq), a positive multiple of colmean, so sign matches)
__global__ __launch_bounds__(256) void qm_dot(const float* __restrict__ x,
                                              const float* __restrict__ cvec,
                                              float* __restrict__ qm) {
    const int w = threadIdx.x >> 6, l = threadIdx.x & 63;
    const int row = blockIdx.x * 4 + w;
    const float* r = x + (size_t)row * DDIM;
    float s = 0.f;
#pragma unroll
    for (int i = 0; i < 4; ++i) {
        float4 v = *(const float4*)(r + i * 256 + l * 4);
        float4 c = *(const float4*)(cvec + i * 256 + l * 4);
        s += v.x * c.x + v.y * c.y + v.z * c.z + v.w * c.w;
    }
#pragma unroll
    for (int off = 32; off; off >>= 1) s += __shfl_down(s, off);
    if (l == 0) qm[row] = s;
}

// ---------------------------------------------------------------------------
// 2) radix-select top-32 (value desc, tie -> lower index) of 32768 floats.
__global__ __launch_bounds__(1024) void topk_radix(const float* __restrict__ sarr,
                                                   int* __restrict__ idx_out) {
    const float* s = sarr + blockIdx.x * MKEYS;
    int* out = idx_out + blockIdx.x * KSEL;
    const int t = threadIdx.x;

    __shared__ int   hist[4096];
    __shared__ int   csum[64];
    __shared__ int   binB_s;
    __shared__ int   ccnt;
    __shared__ float cval[1024];
    __shared__ int   cidx[1024];

    for (int i = t; i < 4096; i += 1024) hist[i] = 0;
    if (t == 0) ccnt = 0;
    __syncthreads();

    for (int j = 0; j < 32; ++j) {
        unsigned u = __float_as_uint(s[t + j * 1024]);
        unsigned k = u ^ (unsigned)(((int)u >> 31) | (int)0x80000000);
        atomicAdd(&hist[k >> 20], 1);
    }
    __syncthreads();

    if (t < 64) {
        int acc = 0;
        for (int j = 0; j < 64; ++j) acc += hist[t * 64 + j];
        csum[t] = acc;
    }
    __syncthreads();
    if (t == 0) {
        int acc = 0, cb = 63;
        for (; cb > 0; --cb) {
            if (acc + csum[cb] >= KSEL) break;
            acc += csum[cb];
        }
        int b = cb * 64 + 63;
        for (; b > cb * 64; --b) {
            if (acc + hist[b] >= KSEL) break;
            acc += hist[b];
        }
        binB_s = b;
    }
    __syncthreads();
    const unsigned binB = (unsigned)binB_s;

    for (int j = 0; j < 32; ++j) {
        const int ii = t + j * 1024;
        float v = s[ii];
        unsigned u = __float_as_uint(v);
        unsigned k = u ^ (unsigned)(((int)u >> 31) | (int)0x80000000);
        if ((k >> 20) >= binB) {
            int p = atomicAdd(&ccnt, 1);
            if (p < 1024) { cval[p] = v; cidx[p] = ii; }
        }
    }
    __syncthreads();

    const int n = min(ccnt, 1024);
    if (t < 64) {
        for (int iter = 0; iter < KSEL; ++iter) {
            float bv = -INFINITY; int bi = 0x7fffffff; int bs = -1;
            for (int j = t; j < n; j += 64) {
                float v = cval[j]; int ii = cidx[j];
                if (v > bv || (v == bv && ii < bi)) { bv = v; bi = ii; bs = j; }
            }
#pragma unroll
            for (int off = 32; off; off >>= 1) {
                float ov = __shfl_down(bv, off);
                int   oi = __shfl_down(bi, off);
                int   os = __shfl_down(bs, off);
                if (ov > bv || (ov == bv && oi < bi)) { bv = ov; bi = oi; bs = os; }
            }
            bs = __shfl(bs, 0);
            if (t == 0) {
                out[iter] = bi;
                cval[bs] = -INFINITY;
            }
        }
    }
}

// ---------------------------------------------------------------------------
// 3) bf16 MFMA GEMM, no LDS: C[M,1024] = A[M,1024] x B[1024,1024]^T.
__global__ __launch_bounds__(256) void gemm_mfma(const unsigned short* __restrict__ A,
                                                 const unsigned short* __restrict__ Bm,
                                                 float* __restrict__ C) {
    const int lane = threadIdx.x & 63, wave = threadIdx.x >> 6;
    const int quad = lane >> 4, l16 = lane & 15;
    const int m0 = blockIdx.y * 128 + (wave >> 1) * 64;
    const int n0 = blockIdx.x * 128 + (wave & 1) * 64;
    const unsigned short* ap = A + (size_t)(m0 + l16) * DDIM + quad * 8;
    const unsigned short* bp = Bm + (size_t)(n0 + l16) * DDIM + quad * 8;

    const f32x4 fzero = {0.f, 0.f, 0.f, 0.f};
    f32x4 acc[4][4];
#pragma unroll
    for (int i = 0; i < 4; ++i)
#pragma unroll
        for (int j = 0; j < 4; ++j) acc[i][j] = fzero;

    for (int k0 = 0; k0 < DDIM; k0 += 32) {
        bf16x8 af[4], bfr[4];
#pragma unroll
        for (int i = 0; i < 4; ++i)
            af[i] = *(const bf16x8*)(ap + (size_t)i * 16 * DDIM + k0);
#pragma unroll
        for (int j = 0; j < 4; ++j)
            bfr[j] = *(const bf16x8*)(bp + (size_t)j * 16 * DDIM + k0);
#pragma unroll
        for (int i = 0; i < 4; ++i)
#pragma unroll
            for (int j = 0; j < 4; ++j)
                acc[i][j] = __builtin_amdgcn_mfma_f32_16x16x32_bf16(af[i], bfr[j], acc[i][j], 0, 0, 0);
    }
    // C/D layout: col = lane&15, row = quad*4 + reg
#pragma unroll
    for (int i = 0; i < 4; ++i) {
        const int row0 = m0 + i * 16 + quad * 4;
#pragma unroll
        for (int j = 0; j < 4; ++j) {
            const int col = n0 + j * 16 + l16;
#pragma unroll
            for (int r = 0; r < 4; ++r)
                C[(size_t)(row0 + r) * DDIM + col] = acc[i][j][r];
        }
    }
}

// ---------------------------------------------------------------------------
// 4) K/V projection of the 64 selected rows (gather fp32 -> bf16 in-register).
__global__ __launch_bounds__(256) void gemm_kv_mfma(
        const float* __restrict__ mk, const float* __restrict__ mv,
        const unsigned short* __restrict__ wkb, const unsigned short* __restrict__ wvb,
        float* __restrict__ kp, float* __restrict__ vp,
        const int* __restrict__ gidx) {
    const float* A = blockIdx.y ? mv : mk;
    const unsigned short* Bm = blockIdx.y ? wvb : wkb;
    float* C = blockIdx.y ? vp : kp;
    const int lane = threadIdx.x & 63, wave = threadIdx.x >> 6;
    const int quad = lane >> 4, l16 = lane & 15;
    const int n0 = blockIdx.x * 256 + wave * 64;

    size_t arow[4];
#pragma unroll
    for (int i = 0; i < 4; ++i) arow[i] = (size_t)gidx[i * 16 + l16] * DDIM;

    const f32x4 fzero = {0.f, 0.f, 0.f, 0.f};
    f32x4 acc[4][4];
#pragma unroll
    for (int i = 0; i < 4; ++i)
#pragma unroll
        for (int j = 0; j < 4; ++j) acc[i][j] = fzero;

    for (int k0 = 0; k0 < DDIM; k0 += 32) {
        bf16x8 af[4], bfr[4];
#pragma unroll
        for (int i = 0; i < 4; ++i) {
            const float* p = A + arow[i] + k0 + quad * 8;
            float4 v0 = *(const float4*)(p);
            float4 v1 = *(const float4*)(p + 4);
            af[i][0] = (short)f2bf(v0.x); af[i][1] = (short)f2bf(v0.y);
            af[i][2] = (short)f2bf(v0.z); af[i][3] = (short)f2bf(v0.w);
            af[i][4] = (short)f2bf(v1.x); af[i][5] = (short)f2bf(v1.y);
            af[i][6] = (short)f2bf(v1.z); af[i][7] = (short)f2bf(v1.w);
        }
#pragma unroll
        for (int j = 0; j < 4; ++j)
            bfr[j] = *(const bf16x8*)(Bm + (size_t)(n0 + j * 16 + l16) * DDIM + k0 + quad * 8);
#pragma unroll
        for (int i = 0; i < 4; ++i)
#pragma unroll
            for (int j = 0; j < 4; ++j)
                acc[i][j] = __builtin_amdgcn_mfma_f32_16x16x32_bf16(af[i], bfr[j], acc[i][j], 0, 0, 0);
    }
#pragma unroll
    for (int i = 0; i < 4; ++i) {
        const int row0 = i * 16 + quad * 4;
#pragma unroll
        for (int j = 0; j < 4; ++j) {
            const int col = n0 + j * 16 + l16;
#pragma unroll
            for (int r = 0; r < 4; ++r)
                C[(size_t)(row0 + r) * DDIM + col] = acc[i][j][r];
        }
    }
}

// ---------------------------------------------------------------------------
// 5) attention: one block per token; writes ctx as bf16 (feeds the o-GEMM),
//    plus avg_attn and sel_idx (as float) straight into d_out.
__global__ __launch_bounds__(256) void attention_kernel(const float* __restrict__ q_full,
                                                        const float* __restrict__ qm,
                                                        const float* __restrict__ kp,
                                                        const float* __restrict__ vp,
                                                        const int* __restrict__ idx_list,
                                                        unsigned short* __restrict__ ctxb,
                                                        float* __restrict__ out) {
    const int bn = blockIdx.x;
    const int t = threadIdx.x;
    __shared__ float qs[DDIM];
    __shared__ float sc[NHEAD][KSEL + 1];
    __shared__ int selbase_s;

    *(float4*)(qs + t * 4) = *(const float4*)(q_full + (size_t)bn * DDIM + t * 4);
    if (t == 0) selbase_s = (qm[bn] > 0.0f) ? 0 : KSEL;
    __syncthreads();
    const int selbase = selbase_s;

#pragma unroll
    for (int p = 0; p < 2; ++p) {
        const int pair = t + p * 256;
        const int h = pair >> 5, k = pair & 31;
        const float* kr = kp + (size_t)(selbase + k) * DDIM + h * HDIM;
        const float* qr = qs + h * HDIM;
        float acc = 0.f;
#pragma unroll
        for (int i = 0; i < 16; ++i) {
            float4 kv = *(const float4*)(kr + i * 4);
            acc += qr[i * 4 + 0] * kv.x + qr[i * 4 + 1] * kv.y +
                   qr[i * 4 + 2] * kv.z + qr[i * 4 + 3] * kv.w;
        }
        sc[h][k] = acc * 0.125f;
    }
    __syncthreads();

    if (t < NHEAD) {
        float m = -INFINITY;
        for (int k = 0; k < KSEL; ++k) m = fmaxf(m, sc[t][k]);
        float ssum = 0.f;
        for (int k = 0; k < KSEL; ++k) { float e = __expf(sc[t][k] - m); sc[t][k] = e; ssum += e; }
        float inv = 1.f / ssum;
        for (int k = 0; k < KSEL; ++k) sc[t][k] *= inv;
    }
    __syncthreads();

#pragma unroll
    for (int c = 0; c < 4; ++c) {
        const int o = c * 256 + t;
        const int h = o >> 6;
        float acc = 0.f;
        for (int k = 0; k < KSEL; ++k)
            acc += sc[h][k] * vp[(size_t)(selbase + k) * DDIM + o];
        ctxb[(size_t)bn * DDIM + o] = f2bf(acc);
    }

    if (t < KSEL) {
        float a = 0.f;
#pragma unroll
        for (int h = 0; h < NHEAD; ++h) a += sc[h][t];
        out[OUT_AVG + bn * KSEL + t] = a * (1.f / 16.f);
        out[OUT_IDX + bn * KSEL + t] = (float)idx_list[selbase + t];
    }
}

// ---------------------------------------------------------------------------
// 6) LayerNorm row kernel
__global__ __launch_bounds__(256) void ln_kernel(const float* __restrict__ raw,
                                                 const float* __restrict__ bo,
                                                 const float* __restrict__ gamma,
                                                 const float* __restrict__ beta,
                                                 float* __restrict__ out) {
    const int row = blockIdx.x;
    const int t = threadIdx.x;
    float4 v = *(const float4*)(raw + (size_t)row * DDIM + t * 4);
    float4 b = *(const float4*)(bo + t * 4);
    v.x += b.x; v.y += b.y; v.z += b.z; v.w += b.w;
    float s  = v.x + v.y + v.z + v.w;
    float ss = v.x * v.x + v.y * v.y + v.z * v.z + v.w * v.w;
#pragma unroll
    for (int off = 32; off; off >>= 1) {
        s  += __shfl_down(s, off);
        ss += __shfl_down(ss, off);
    }
    __shared__ float rs[4], rss[4];
    const int w = t >> 6, l = t & 63;
    if (l == 0) { rs[w] = s; rss[w] = ss; }
    __syncthreads();
    if (t == 0) {
        rs[0]  = rs[0] + rs[1] + rs[2] + rs[3];
        rss[0] = rss[0] + rss[1] + rss[2] + rss[3];
    }
    __syncthreads();
    const float mu  = rs[0] * (1.f / 1024.f);
    const float var = rss[0] * (1.f / 1024.f) - mu * mu;
    const float rstd = rsqrtf(var + 1e-5f);
    float4 g  = *(const float4*)(gamma + t * 4);
    float4 be = *(const float4*)(beta + t * 4);
    float4 o;
    o.x = (v.x - mu) * rstd * g.x + be.x;
    o.y = (v.y - mu) * rstd * g.y + be.y;
    o.z = (v.z - mu) * rstd * g.z + be.z;
    o.w = (v.w - mu) * rstd * g.w + be.w;
    *(float4*)(out + (size_t)row * DDIM + t * 4) = o;
}

// ---------------------------------------------------------------------------
extern "C" void kernel_launch(void* const* d_in, const int* in_sizes, int n_in,
                              void* d_out, int out_size, void* d_ws, size_t ws_size,
                              hipStream_t stream) {
    const float* x     = (const float*)d_in[0];
    const float* mk    = (const float*)d_in[1];
    const float* mv    = (const float*)d_in[2];
    const float* Wq    = (const float*)d_in[3];
    const float* Wk    = (const float*)d_in[4];
    const float* Wv    = (const float*)d_in[5];
    const float* Wo    = (const float*)d_in[6];
    const float* bo    = (const float*)d_in[7];
    const float* gamma = (const float*)d_in[8];
    const float* beta  = (const float*)d_in[9];

    float* ws  = (float*)d_ws;
    float* out = (float*)d_out;

    float* q_full          = ws + WS_QFULL;
    unsigned short* ctxb   = (unsigned short*)(ws + WS_CTXB);
    float* sarr            = ws + WS_S;
    float* qm              = ws + WS_QM;
    float* kp              = ws + WS_KP;
    float* vp              = ws + WS_VP;
    int*   idx             = (int*)(ws + WS_IDX);
    unsigned short* xb     = (unsigned short*)(ws + WS_XB);
    unsigned short* wqb    = (unsigned short*)(ws + WS_WQB);
    unsigned short* wkb    = (unsigned short*)(ws + WS_WKB);
    unsigned short* wvb    = (unsigned short*)(ws + WS_WVB);
    unsigned short* wob    = (unsigned short*)(ws + WS_WOB);
    float* cvec            = ws + WS_CVEC;
    float* raw             = ws + WS_RAW;   // aliases q_full (dead after attention)

    hipMemsetAsync(cvec, 0, DDIM * sizeof(float), stream);
    hipLaunchKernelGGL(prep_kernel, dim3(14400), dim3(256), 0, stream,
                       mk, x, Wq, Wk, Wv, Wo, sarr, sarr + MKEYS,
                       xb, wqb, wkb, wvb, wob, cvec);
    hipLaunchKernelGGL(qm_dot, dim3(BTOK / 4), dim3(256), 0, stream, x, cvec, qm);
    hipLaunchKernelGGL(topk_radix, dim3(2), dim3(1024), 0, stream, sarr, idx);
    hipLaunchKernelGGL(gemm_mfma, dim3(8, 16), dim3(256), 0, stream, xb, wqb, q_full);
    hipLaunchKernelGGL(gemm_kv_mfma, dim3(4, 2), dim3(256), 0, stream, mk, mv, wkb, wvb, kp, vp, idx);
    hipLaunchKernelGGL(attention_kernel, dim3(BTOK), dim3(256), 0, stream, q_full, qm, kp, vp, idx, ctxb, out);
    hipLaunchKernelGGL(gemm_mfma, dim3(8, 16), dim3(256), 0, stream, ctxb, wob, raw);
    hipLaunchKernelGGL(ln_kernel, dim3(BTOK), dim3(256), 0, stream, raw, bo, gamma, beta, out);
}